// Round 2
// baseline (512.607 us; speedup 1.0000x reference)
//
#include <hip/hip_runtime.h>
#include <cstdint>
#include <cstddef>

typedef float v4f __attribute__((ext_vector_type(4)));
typedef short short8 __attribute__((ext_vector_type(8)));
typedef unsigned short ushort_t;

constexpr int B_ = 8, P_ = 16384, Q_ = 256, E_ = 128;

// ---------- helpers ----------
__device__ __forceinline__ unsigned int f2bf(float f) {
  unsigned int x = __float_as_uint(f);
  x += 0x7FFFu + ((x >> 16) & 1u);           // round-to-nearest-even
  return x >> 16;
}
__device__ __forceinline__ float softplus_f(float x) {
  return fmaxf(x, 0.f) + __logf(1.f + __expf(-fabsf(x)));
}
__device__ __forceinline__ void gload16(const void* g, void* l) {
  __builtin_amdgcn_global_load_lds((const __attribute__((address_space(1))) void*)g,
                                   (__attribute__((address_space(3))) void*)l,
                                   16, 0, 0);
}

// ---------- P1: row pass + in-block transpose to fragment-tile layout ----------
// Output layout: A1T/PPT[b][cp][q][64] bf16, cp = p>>6; within each 128B q-row the
// 16B chunk index is XOR-swizzled by (q&7) so gemm's ds_read_b128 is conflict-free.
__global__ __launch_bounds__(256, 4) void prep_rows(
    const float* __restrict__ mlv, const int* __restrict__ mask,
    ushort_t* __restrict__ A1T, ushort_t* __restrict__ PPT,
    float* __restrict__ negsum, float* __restrict__ ppsum)
{
  __shared__ unsigned int st[256 * 33];   // staging tile: 256 q-rows x 33 words (2 pad shorts)
  const int t = threadIdx.x, w = t >> 6, l = t & 63;
  const int b = blockIdx.x >> 8, cp = blockIdx.x & 255;
  const size_t base = ((size_t)b * P_ + cp * 64) * Q_;
  float accN[4] = {0.f,0.f,0.f,0.f}, accP[4] = {0.f,0.f,0.f,0.f};
  unsigned int a1w[4][4][2], ppw[4][4][2];   // [group][j(q=l+64j)][half]: ushort4 along p

#pragma unroll
  for (int g = 0; g < 4; ++g) {
#pragma unroll
    for (int j = 0; j < 4; ++j) { a1w[g][j][0]=0; a1w[g][j][1]=0; ppw[g][j][0]=0; ppw[g][j][1]=0; }
#pragma unroll
    for (int r = 0; r < 4; ++r) {
      const int pl = (w << 4) + (g << 2) + r;            // p within chunk
      const float* xp = mlv + base + (size_t)pl * Q_ + l;
      const int*   mp = mask + base + (size_t)pl * Q_ + l;
      float xs[4]; int ms[4];
#pragma unroll
      for (int j = 0; j < 4; ++j) { xs[j] = xp[j * 64]; ms[j] = mp[j * 64]; }
      float ev[4]; float s = 0.f;
#pragma unroll
      for (int j = 0; j < 4; ++j) {
        const bool mm = ms[j] != 0;
        const float xv = xs[j];
        const float e = mm ? __expf(xv) : 0.f;           // |x|<~6, no max-shift needed
        ev[j] = e; s += e;
        accN[j] += __logf(1.f + e);                      // softplus(x), 0 when unmasked
        a1w[g][j][r >> 1] |= f2bf(mm ? -xv : 0.f) << ((r & 1) * 16);
      }
#pragma unroll
      for (int o = 32; o; o >>= 1) s += __shfl_xor(s, o, 64);
      const float inv = (s > 0.f) ? (1.f / s) : 0.f;
#pragma unroll
      for (int j = 0; j < 4; ++j) {
        const float p = ev[j] * inv;
        accP[j] += p;
        ppw[g][j][r >> 1] |= f2bf(p) << ((r & 1) * 16);
      }
    }
  }
  const size_t tb = ((size_t)(b * 256 + cp)) * 16384;    // elems
  // ---- dump A1 tile ----
#pragma unroll
  for (int g = 0; g < 4; ++g)
#pragma unroll
    for (int j = 0; j < 4; ++j) {
      const int wb = (l + (j << 6)) * 33 + (w << 3) + (g << 1);
      st[wb] = a1w[g][j][0]; st[wb + 1] = a1w[g][j][1];
    }
  __syncthreads();
  {
    uint4* dst = (uint4*)(A1T + tb);
#pragma unroll
    for (int pass = 0; pass < 8; ++pass) {
      const int gi = pass * 256 + t;
      const int q = gi >> 3, c = (gi & 7) ^ (q & 7);     // swizzle baked into global
      const int wd = q * 33 + c * 4;
      uint4 v; v.x = st[wd]; v.y = st[wd+1]; v.z = st[wd+2]; v.w = st[wd+3];
      dst[gi] = v;
    }
  }
  __syncthreads();
  // ---- dump PP tile ----
#pragma unroll
  for (int g = 0; g < 4; ++g)
#pragma unroll
    for (int j = 0; j < 4; ++j) {
      const int wb = (l + (j << 6)) * 33 + (w << 3) + (g << 1);
      st[wb] = ppw[g][j][0]; st[wb + 1] = ppw[g][j][1];
    }
  __syncthreads();
  {
    uint4* dst = (uint4*)(PPT + tb);
#pragma unroll
    for (int pass = 0; pass < 8; ++pass) {
      const int gi = pass * 256 + t;
      const int q = gi >> 3, c = (gi & 7) ^ (q & 7);
      const int wd = q * 33 + c * 4;
      uint4 v; v.x = st[wd]; v.y = st[wd+1]; v.z = st[wd+2]; v.w = st[wd+3];
      dst[gi] = v;
    }
  }
  __syncthreads();
  // ---- column-sum reductions ----
  float* red = (float*)st;
#pragma unroll
  for (int j = 0; j < 4; ++j) red[w * 256 + l + (j << 6)] = accN[j];
  __syncthreads();
  {
    const float sn = red[t] + red[256 + t] + red[512 + t] + red[768 + t];
    atomicAdd(&negsum[b * 256 + t], sn);
  }
  __syncthreads();
#pragma unroll
  for (int j = 0; j < 4; ++j) red[w * 256 + l + (j << 6)] = accP[j];
  __syncthreads();
  {
    const float sq = red[t] + red[256 + t] + red[512 + t] + red[768 + t];
    atomicAdd(&ppsum[b * 256 + t], sq);
  }
}

// ---------- P2: segmap -> transposed bf16 (raw + binarized) + col sums + nnz ----------
__global__ __launch_bounds__(256, 4) void prep_seg(
    const float* __restrict__ seg, ushort_t* __restrict__ SGT, ushort_t* __restrict__ SGB,
    float* __restrict__ segsum, float* __restrict__ nnzb)
{
  __shared__ unsigned int st[128 * 33];   // 128 e-rows x 33 words
  const int t = threadIdx.x, w = t >> 6, l = t & 63;
  const int b = blockIdx.x >> 8, cp = blockIdx.x & 255;
  const size_t base = ((size_t)b * P_ + cp * 64) * E_;
  float accS[2] = {0.f, 0.f}; float cnt = 0.f;
  unsigned int sgw[4][2][2], sbw[4][2][2];
#pragma unroll
  for (int g = 0; g < 4; ++g) {
#pragma unroll
    for (int j = 0; j < 2; ++j) { sgw[g][j][0]=0; sgw[g][j][1]=0; sbw[g][j][0]=0; sbw[g][j][1]=0; }
#pragma unroll
    for (int r = 0; r < 4; ++r) {
      const int pl = (w << 4) + (g << 2) + r;
      const float* vp = seg + base + (size_t)pl * E_ + l;
#pragma unroll
      for (int j = 0; j < 2; ++j) {
        const float v = vp[j * 64];
        const bool nz = v > 0.f;
        accS[j] += v; cnt += nz ? 1.f : 0.f;
        sgw[g][j][r >> 1] |= f2bf(v) << ((r & 1) * 16);
        sbw[g][j][r >> 1] |= (nz ? 0x3F80u : 0u) << ((r & 1) * 16);
      }
    }
  }
  const size_t tb = ((size_t)(b * 256 + cp)) * 8192;
  // raw
#pragma unroll
  for (int g = 0; g < 4; ++g)
#pragma unroll
    for (int j = 0; j < 2; ++j) {
      const int wb = (l + (j << 6)) * 33 + (w << 3) + (g << 1);
      st[wb] = sgw[g][j][0]; st[wb + 1] = sgw[g][j][1];
    }
  __syncthreads();
  {
    uint4* dst = (uint4*)(SGT + tb);
#pragma unroll
    for (int pass = 0; pass < 4; ++pass) {
      const int gi = pass * 256 + t;
      const int q = gi >> 3, c = (gi & 7) ^ (q & 7);
      const int wd = q * 33 + c * 4;
      uint4 v; v.x = st[wd]; v.y = st[wd+1]; v.z = st[wd+2]; v.w = st[wd+3];
      dst[gi] = v;
    }
  }
  __syncthreads();
  // binarized
#pragma unroll
  for (int g = 0; g < 4; ++g)
#pragma unroll
    for (int j = 0; j < 2; ++j) {
      const int wb = (l + (j << 6)) * 33 + (w << 3) + (g << 1);
      st[wb] = sbw[g][j][0]; st[wb + 1] = sbw[g][j][1];
    }
  __syncthreads();
  {
    uint4* dst = (uint4*)(SGB + tb);
#pragma unroll
    for (int pass = 0; pass < 4; ++pass) {
      const int gi = pass * 256 + t;
      const int q = gi >> 3, c = (gi & 7) ^ (q & 7);
      const int wd = q * 33 + c * 4;
      uint4 v; v.x = st[wd]; v.y = st[wd+1]; v.z = st[wd+2]; v.w = st[wd+3];
      dst[gi] = v;
    }
  }
  __syncthreads();
  float* red = (float*)st;
#pragma unroll
  for (int j = 0; j < 2; ++j) red[w * 128 + l + (j << 6)] = accS[j];
  __syncthreads();
  if (t < 128) {
    const float ss = red[t] + red[128 + t] + red[256 + t] + red[384 + t];
    atomicAdd(&segsum[b * 128 + t], ss);
  }
#pragma unroll
  for (int o = 32; o; o >>= 1) cnt += __shfl_xor(cnt, o, 64);
  if (l == 0) atomicAdd(&nnzb[b], cnt);
}

// ---------- GEMM: m97-style, global_load_lds staging, split-K via fp32 atomics ----------
// grid = 8b x 2g x 2qt x 16ks = 512 blocks. Operands already in fragment-tile layout.
__global__ __launch_bounds__(256, 2) void gemm_mfma(
    const ushort_t* __restrict__ A1T, const ushort_t* __restrict__ PPT,
    const ushort_t* __restrict__ SGT, const ushort_t* __restrict__ SGB,
    float* __restrict__ part)
{
  __shared__ __align__(16) char lds[32768];   // A tile 16KB @0, B tile 16KB @16384
  const int id = blockIdx.x;
  const int ks = id & 15, qt = (id >> 4) & 1, g = (id >> 5) & 1, b = id >> 6;
  const ushort_t* Aall = g ? PPT : A1T;
  const ushort_t* Ball = g ? SGT : SGB;
  const int t = threadIdx.x, l = t & 63, w = t >> 6;
  const int lm = l & 15, quad = l >> 4;
  const int wm = w & 1, wn = w >> 1;
  v4f acc[4][4];
#pragma unroll
  for (int i = 0; i < 4; ++i)
#pragma unroll
    for (int j = 0; j < 4; ++j) acc[i][j] = (v4f)0.f;
  const size_t cp0 = (size_t)b * 256 + ks * 16;
  const char* gA = (const char*)(Aall + cp0 * 16384 + qt * 8192);
  const char* gB = (const char*)(Ball + cp0 * 8192);
  const int off = t * 16;

  for (int it = 0; it < 16; ++it) {
    __syncthreads();
    const char* pa = gA + (size_t)it * 32768;
    const char* pb = gB + (size_t)it * 16384;
    gload16(pa + off,          lds + off);
    gload16(pa + off + 4096,   lds + off + 4096);
    gload16(pa + off + 8192,   lds + off + 8192);
    gload16(pa + off + 12288,  lds + off + 12288);
    gload16(pb + off,          lds + 16384 + off);
    gload16(pb + off + 4096,   lds + 16384 + off + 4096);
    gload16(pb + off + 8192,   lds + 16384 + off + 8192);
    gload16(pb + off + 12288,  lds + 16384 + off + 12288);
    __syncthreads();
#pragma unroll
    for (int k32 = 0; k32 < 2; ++k32) {
      short8 af[4], bf[4];
      const int ach = ((k32 << 2) | quad) ^ (lm & 7);    // un-swizzle -> conflict-free
#pragma unroll
      for (int i = 0; i < 4; ++i) {
        af[i] = *(const short8*)(lds + (wm * 64 + i * 16 + lm) * 128 + ach * 16);
        bf[i] = *(const short8*)(lds + 16384 + (wn * 64 + i * 16 + lm) * 128 + ach * 16);
      }
#pragma unroll
      for (int i = 0; i < 4; ++i)
#pragma unroll
        for (int j = 0; j < 4; ++j)
          acc[i][j] = __builtin_amdgcn_mfma_f32_16x16x32_bf16(af[i], bf[j], acc[i][j], 0, 0, 0);
    }
  }
  float* pout = part + (size_t)(g * 8 + b) * 32768;
#pragma unroll
  for (int i = 0; i < 4; ++i)
#pragma unroll
    for (int r = 0; r < 4; ++r) {
      const int q = qt * 128 + wm * 64 + i * 16 + quad * 4 + r;
#pragma unroll
      for (int j = 0; j < 4; ++j) {
        const int e = wn * 64 + j * 16 + lm;
        atomicAdd(&pout[q * 128 + e], acc[i][j][r]);
      }
    }
}

// ---------- epilogue: all closed-form cost terms ----------
__global__ __launch_bounds__(128) void epilogue(
    const float* __restrict__ part,
    const float* __restrict__ negsum, const float* __restrict__ ppsum,
    const float* __restrict__ segsum, const float* __restrict__ nnzb,
    const float* __restrict__ logits, const float* __restrict__ ppos,
    const float* __restrict__ chol, const float* __restrict__ tpos,
    const float* __restrict__ imgsz, float* __restrict__ out)
{
  const int bq = blockIdx.x;          // b*256 + q
  const int b = bq >> 8;
  const int e = threadIdx.x;
  const int qe = (bq & 255) * 128 + e;
  const float g1 = part[(size_t)b * 32768 + qe];
  const float g2 = part[(size_t)(8 + b) * 32768 + qe];

  const float nnz = fmaxf(nnzb[b], 1.f);
  const float mask_cost = (negsum[bq] + g1) / nnz;
  const float dice = 1.f - (2.f * g2 + 1.f) / (ppsum[bq] + segsum[b * 128 + e] + 1.f);
  const float cls = softplus_f(-logits[bq]);
  const float px = ppos[bq * 2], py = ppos[bq * 2 + 1];
  const float tx = tpos[(b * 128 + e) * 2], ty = tpos[(b * 128 + e) * 2 + 1];
  const float dx = px - tx, dy = py - ty;
  const float ax = fabsf(dx), ay = fabsf(dy);
  const float hx = (ax < 1.f) ? 0.5f * dx * dx : ax - 0.5f;
  const float hy = (ay < 1.f) ? 0.5f * dy * dy : ay - 0.5f;
  const float huber = 0.5f * (hx + hy);
  const float sx = imgsz[b * 2], sy = imgsz[b * 2 + 1];
  const float L00 = chol[bq * 4 + 0], L10 = chol[bq * 4 + 2], L11 = chol[bq * 4 + 3];
  const float d0 = (tx - px) * sx, d1 = (ty - py) * sy;
  const float z0 = d0 / L00;
  const float z1 = (d1 - L10 * z0) / L11;
  const float nll = 0.5f * (z0 * z0 + z1 * z1) + 1.8378770664093453f + __logf(L00) + __logf(L11);
  const float lik = 1.f - __expf(-nll);
  out[bq * 128 + e] = 2.f * cls + 5.f * mask_cost + 5.f * dice + huber + 0.5f * nll + 0.5f * lik;
}

// ---------- launcher ----------
extern "C" void kernel_launch(void* const* d_in, const int* in_sizes, int n_in,
                              void* d_out, int out_size, void* d_ws, size_t ws_size,
                              hipStream_t stream)
{
  (void)in_sizes; (void)n_in; (void)out_size; (void)ws_size;
  const float* logits = (const float*)d_in[0];
  const float* mlv    = (const float*)d_in[1];
  const int*   mask   = (const int*)d_in[2];
  const float* seg    = (const float*)d_in[3];
  const float* ppos   = (const float*)d_in[4];
  const float* chol   = (const float*)d_in[5];
  const float* tpos   = (const float*)d_in[6];
  const float* imgsz  = (const float*)d_in[7];

  char* ws = (char*)d_ws;
  ushort_t* A1T = (ushort_t*)(ws);                 //  67108864 B
  ushort_t* PPT = (ushort_t*)(ws + 67108864);      //  67108864 B
  ushort_t* SGT = (ushort_t*)(ws + 134217728);     //  33554432 B
  ushort_t* SGB = (ushort_t*)(ws + 167772160);     //  33554432 B
  float* part   = (float*)(ws + 201326592);        //   2097152 B  [2][8][256][128]
  float* negsum = (float*)(ws + 203423744);        //   8192 B
  float* ppsum  = (float*)(ws + 203431936);        //   8192 B
  float* segsum = (float*)(ws + 203440128);        //   4096 B
  float* nnzb   = (float*)(ws + 203444224);        //   32 B

  hipMemsetAsync(ws + 201326592, 0, 2117696, stream);
  prep_seg<<<2048, 256, 0, stream>>>(seg, SGT, SGB, segsum, nnzb);
  prep_rows<<<2048, 256, 0, stream>>>(mlv, mask, A1T, PPT, negsum, ppsum);
  gemm_mfma<<<512, 256, 0, stream>>>(A1T, PPT, SGT, SGB, part);
  epilogue<<<2048, 128, 0, stream>>>(part, negsum, ppsum, segsum, nnzb,
                                     logits, ppos, chol, tpos, imgsz, (float*)d_out);
}